// Round 1
// baseline (287.523 us; speedup 1.0000x reference)
//
#include <hip/hip_runtime.h>

#define HID 2048
#define NEXP 64
#define NTOK 16384
#define TM 64            // tokens per block
#define BK 128           // H chunk
#define NTHREADS 256
#define NCHUNK (HID / BK)   // 16

#define XS_STRIDE 132    // 128 + 4 pad (float units)
#define WS_STRIDE 68     // 64 + 4 pad  (float units)

// out layout (float32): weights [0,32768) | indices [32768,65536) | aux 65536 | counts [65537,65601)
#define OUT_IDX_OFF (2 * NTOK)
#define OUT_AUX_OFF (4 * NTOK)
#define OUT_CNT_OFF (4 * NTOK + 1)

__global__ __launch_bounds__(NTHREADS) void router_main(
    const float* __restrict__ x, const float* __restrict__ W,
    float* __restrict__ out, float* __restrict__ ws_accum)
{
    __shared__ float xs[TM * XS_STRIDE];      // 33792 B
    __shared__ float wsh[BK * WS_STRIDE];     // 34816 B (reused as logits[64][68] in epilogue)
    __shared__ float smax[TM];
    __shared__ float sinvZ[TM];
    __shared__ float scount[NEXP];

    const int tid = threadIdx.x;
    const int n0 = blockIdx.x * TM;
    const int ty = tid >> 4;    // 0..15 : token group (4 tokens)
    const int tx = tid & 15;    // 0..15 : expert group (4 experts)

    float acc[4][4];
#pragma unroll
    for (int i = 0; i < 4; i++)
#pragma unroll
        for (int j = 0; j < 4; j++) acc[i][j] = 0.f;

    float4 ax[8];   // x prefetch: f4 = tid + 256*i -> t=f4>>5, k4=f4&31
    float4 aw[8];   // W prefetch: f4 = tid + 256*i -> e=f4&63, kk=f4>>6

    // prefetch chunk 0
#pragma unroll
    for (int i = 0; i < 8; i++) {
        int f4 = tid + NTHREADS * i;
        int t = f4 >> 5, k4 = f4 & 31;
        ax[i] = *(const float4*)(x + (size_t)(n0 + t) * HID + k4 * 4);
    }
#pragma unroll
    for (int i = 0; i < 8; i++) {
        int f4 = tid + NTHREADS * i;
        int e = f4 & 63, kk = f4 >> 6;
        aw[i] = *(const float4*)(W + (size_t)e * HID + kk * 4);
    }

#pragma unroll 1
    for (int c = 0; c < NCHUNK; ++c) {
        // stage prefetched regs -> LDS
#pragma unroll
        for (int i = 0; i < 8; i++) {
            int f4 = tid + NTHREADS * i;
            int t = f4 >> 5, k4 = f4 & 31;
            *(float4*)(&xs[t * XS_STRIDE + k4 * 4]) = ax[i];
        }
#pragma unroll
        for (int i = 0; i < 8; i++) {
            int f4 = tid + NTHREADS * i;
            int e = f4 & 63, kk = f4 >> 6;
            wsh[(4 * kk + 0) * WS_STRIDE + e] = aw[i].x;
            wsh[(4 * kk + 1) * WS_STRIDE + e] = aw[i].y;
            wsh[(4 * kk + 2) * WS_STRIDE + e] = aw[i].z;
            wsh[(4 * kk + 3) * WS_STRIDE + e] = aw[i].w;
        }
        __syncthreads();

        // prefetch chunk c+1 (lands during compute)
        if (c + 1 < NCHUNK) {
            int h0 = (c + 1) * BK;
#pragma unroll
            for (int i = 0; i < 8; i++) {
                int f4 = tid + NTHREADS * i;
                int t = f4 >> 5, k4 = f4 & 31;
                ax[i] = *(const float4*)(x + (size_t)(n0 + t) * HID + h0 + k4 * 4);
            }
#pragma unroll
            for (int i = 0; i < 8; i++) {
                int f4 = tid + NTHREADS * i;
                int e = f4 & 63, kk = f4 >> 6;
                aw[i] = *(const float4*)(W + (size_t)e * HID + h0 + kk * 4);
            }
        }

        // compute this chunk into fresh partials (accuracy: chunked accumulation)
        float cacc[4][4];
#pragma unroll
        for (int i = 0; i < 4; i++)
#pragma unroll
            for (int j = 0; j < 4; j++) cacc[i][j] = 0.f;

#pragma unroll 8
        for (int kk = 0; kk < BK / 4; ++kk) {
            float4 av[4], bv[4];
#pragma unroll
            for (int i = 0; i < 4; i++)
                av[i] = *(const float4*)(&xs[(4 * ty + i) * XS_STRIDE + kk * 4]);
#pragma unroll
            for (int kj = 0; kj < 4; kj++)
                bv[kj] = *(const float4*)(&wsh[(4 * kk + kj) * WS_STRIDE + tx * 4]);
            const float* ap = (const float*)av;   // ap[i*4+kj]
            const float* bp = (const float*)bv;   // bp[kj*4+j]
#pragma unroll
            for (int i = 0; i < 4; i++)
#pragma unroll
                for (int kj = 0; kj < 4; kj++) {
                    float aa = ap[i * 4 + kj];
#pragma unroll
                    for (int j = 0; j < 4; j++)
                        cacc[i][j] += aa * bp[kj * 4 + j];
                }
        }
#pragma unroll
        for (int i = 0; i < 4; i++)
#pragma unroll
            for (int j = 0; j < 4; j++) acc[i][j] += cacc[i][j];

        __syncthreads();
    }

    // ---- epilogue: logits -> LDS (reuse wsh as logits[64][WS_STRIDE]) ----
#pragma unroll
    for (int i = 0; i < 4; i++) {
        float4 v = make_float4(acc[i][0], acc[i][1], acc[i][2], acc[i][3]);
        *(float4*)(&wsh[(4 * ty + i) * WS_STRIDE + tx * 4]) = v;
    }
    if (tid < NEXP) scount[tid] = 0.f;
    __syncthreads();

    // phase A: per-token top-2 + softmax stats + weight/index writes
    if (tid < TM) {
        const int t = tid;
        float m1 = -3.4e38f, m2 = -3.4e38f;
        int i1 = 0, i2 = 0;
        for (int e = 0; e < NEXP; e++) {
            float v = wsh[t * WS_STRIDE + e];
            if (v > m1) { m2 = m1; i2 = i1; m1 = v; i1 = e; }
            else if (v > m2) { m2 = v; i2 = e; }
        }
        float Z = 0.f;
        for (int e = 0; e < NEXP; e++)
            Z += __expf(wsh[t * WS_STRIDE + e] - m1);
        float invZ = 1.f / Z;
        float p1 = invZ;                    // exp(0)/Z
        float p2 = __expf(m2 - m1) * invZ;
        float denom = p1 + p2 + 1e-6f;
        float w1 = p1 / denom, w2 = p2 / denom;
        int n = n0 + t;
        out[2 * n + 0] = w1;
        out[2 * n + 1] = w2;
        out[OUT_IDX_OFF + 2 * n + 0] = (float)i1;
        out[OUT_IDX_OFF + 2 * n + 1] = (float)i2;
        smax[t] = m1;
        sinvZ[t] = invZ;
        atomicAdd(&scount[i1], 1.f);
        atomicAdd(&scount[i2], 1.f);
    }
    __syncthreads();

    // phase B: per-expert prob sum over this block's tokens, then global atomics
    if (tid < NEXP) {
        const int e = tid;
        float s = 0.f;
        for (int t = 0; t < TM; t++)
            s += __expf(wsh[t * WS_STRIDE + e] - smax[t]) * sinvZ[t];
        atomicAdd(&ws_accum[e], s);            // sum of routing probs per expert
        atomicAdd(&ws_accum[NEXP + e], scount[e]);  // counts per expert
    }
}

__global__ void router_finish(const float* __restrict__ ws_accum,
                              float* __restrict__ out)
{
    const int e = threadIdx.x;   // 64 threads = 1 wave
    const float invN = 1.f / (float)NTOK;
    float p = ws_accum[e] * invN;          // prob_per_expert
    float a = ws_accum[NEXP + e] * invN;   // assign_per_expert
    float v = p * p + a * a;
#pragma unroll
    for (int off = 32; off > 0; off >>= 1)
        v += __shfl_down(v, off);
    if (e == 0) out[OUT_AUX_OFF] = v * (float)NEXP;
    out[OUT_CNT_OFF + e] = ws_accum[NEXP + e];
}

extern "C" void kernel_launch(void* const* d_in, const int* in_sizes, int n_in,
                              void* d_out, int out_size, void* d_ws, size_t ws_size,
                              hipStream_t stream)
{
    const float* x = (const float*)d_in[0];   // [4,4096,2048] f32
    const float* W = (const float*)d_in[1];   // [64,2048] f32
    float* out = (float*)d_out;
    float* wsf = (float*)d_ws;

    // zero the accumulator scratch (prob_sum[64] + counts[64]); ws is re-poisoned each run
    hipMemsetAsync(wsf, 0, 2 * NEXP * sizeof(float), stream);

    router_main<<<NTOK / TM, NTHREADS, 0, stream>>>(x, W, out, wsf);
    router_finish<<<1, 64, 0, stream>>>(wsf, out);
}

// Round 2
// 236.694 us; speedup vs baseline: 1.2147x; 1.2147x over previous
//
#include <hip/hip_runtime.h>

#define HID 2048
#define NEXP 64
#define NTOK 16384
#define TM 64            // tokens per block
#define BK 64            // H chunk
#define NTHREADS 256
#define NCHUNK (HID / BK)    // 32
#define RS 72                // plane row stride in bf16 elements (144 B: 2-way bank pattern, free)
#define PLANE_B (64 * RS * 2)        // 9216 B per plane (64 rows)
#define CHUNK_B (3 * PLANE_B)        // 27648 B = 27 x 1024 (exact DMA multiple)
#define WS_W_OFF 1024                // W planes start here in d_ws (accum in [0,512))

// out layout (f32): weights [0,32768) | indices [32768,65536) | aux 65536 | counts [65537,65601)
#define OUT_IDX_OFF (2 * NTOK)
#define OUT_AUX_OFF (4 * NTOK)
#define OUT_CNT_OFF (4 * NTOK + 1)

typedef __attribute__((ext_vector_type(8))) short bhalf8;   // 8 bf16 = 4 VGPRs (MFMA A/B frag)
typedef __attribute__((ext_vector_type(4))) float f32x4;    // MFMA C/D frag

// Exact 3-way RNE bf16 split: v == h1 + h2 + h3 (24-bit significand fully captured).
__device__ __forceinline__ void split3(float v, unsigned short& h1, unsigned short& h2, unsigned short& h3) {
    unsigned int u = __float_as_uint(v);
    unsigned int r1 = (u + 0x7FFFu + ((u >> 16) & 1u)) & 0xFFFF0000u;
    float f1 = __uint_as_float(r1);
    float d1 = v - f1;                               // exact (<=16 bits)
    unsigned int u2 = __float_as_uint(d1);
    unsigned int r2 = (u2 + 0x7FFFu + ((u2 >> 16) & 1u)) & 0xFFFF0000u;
    float f2 = __uint_as_float(r2);
    float d2 = d1 - f2;                              // exact, representable in bf16
    h1 = (unsigned short)(r1 >> 16);
    h2 = (unsigned short)(r2 >> 16);
    h3 = (unsigned short)(__float_as_uint(d2) >> 16);
}

// ---- pre-kernel: split W into 3 bf16 planes, laid out in LDS-tile format ----
// d_ws layout at WS_W_OFF: [chunk c][plane p][expert e][j 0..71] bf16 (pad j>=64 junk, never read)
__global__ __launch_bounds__(256) void wsplit_kernel(const float* __restrict__ W, char* __restrict__ wq) {
    int idx8 = (blockIdx.x * 256 + threadIdx.x) * 8;   // 16384 threads x 8 elems = 131072
    int e = idx8 >> 11;          // expert
    int kk = idx8 & 2047;        // k
    int c = kk >> 6;             // chunk
    int j = kk & 63;             // col within chunk (multiple of 8)
    const float4* wp = (const float4*)(W + (size_t)e * HID + kk);
    float4 v0 = wp[0], v1 = wp[1];
    float f[8] = {v0.x, v0.y, v0.z, v0.w, v1.x, v1.y, v1.z, v1.w};
    unsigned int p1[4], p2[4], p3[4];
#pragma unroll
    for (int t = 0; t < 4; t++) {
        unsigned short a1, a2, a3, b1, b2, b3;
        split3(f[2 * t], a1, a2, a3);
        split3(f[2 * t + 1], b1, b2, b3);
        p1[t] = (unsigned int)a1 | ((unsigned int)b1 << 16);
        p2[t] = (unsigned int)a2 | ((unsigned int)b2 << 16);
        p3[t] = (unsigned int)a3 | ((unsigned int)b3 << 16);
    }
    char* base = wq + (size_t)c * CHUNK_B + e * (RS * 2) + j * 2;
    *(uint4*)(base)               = make_uint4(p1[0], p1[1], p1[2], p1[3]);
    *(uint4*)(base + PLANE_B)     = make_uint4(p2[0], p2[1], p2[2], p2[3]);
    *(uint4*)(base + 2 * PLANE_B) = make_uint4(p3[0], p3[1], p3[2], p3[3]);
}

// ---- main kernel ----
__device__ __forceinline__ void load_x_slot(const float* __restrict__ x, int n0, int c, int s,
                                            float4& a, float4& b) {
    int row = s >> 3, oct = s & 7;
    const float4* gp = (const float4*)(x + (size_t)(n0 + row) * HID + c * BK + oct * 8);
    a = gp[0];
    b = gp[1];
}

__device__ __forceinline__ void conv_store_x(char* xpl, int s, float4 a, float4 b) {
    int row = s >> 3, oct = s & 7;
    float f[8] = {a.x, a.y, a.z, a.w, b.x, b.y, b.z, b.w};
    unsigned int p1[4], p2[4], p3[4];
#pragma unroll
    for (int t = 0; t < 4; t++) {
        unsigned short a1, a2, a3, b1, b2, b3;
        split3(f[2 * t], a1, a2, a3);
        split3(f[2 * t + 1], b1, b2, b3);
        p1[t] = (unsigned int)a1 | ((unsigned int)b1 << 16);
        p2[t] = (unsigned int)a2 | ((unsigned int)b2 << 16);
        p3[t] = (unsigned int)a3 | ((unsigned int)b3 << 16);
    }
    char* base = xpl + row * (RS * 2) + oct * 16;
    *(uint4*)(base)               = make_uint4(p1[0], p1[1], p1[2], p1[3]);
    *(uint4*)(base + PLANE_B)     = make_uint4(p2[0], p2[1], p2[2], p2[3]);
    *(uint4*)(base + 2 * PLANE_B) = make_uint4(p3[0], p3[1], p3[2], p3[3]);
}

__device__ __forceinline__ void dma_w_chunk(const char* gbase, char* lbase, int wave, int lane) {
#pragma unroll
    for (int k = 0; k < 7; k++) {
        int idx = wave + 4 * k;       // 27 instrs of 1024 B across 4 waves (wave-uniform guard)
        if (idx < 27) {
            __builtin_amdgcn_global_load_lds(
                (const __attribute__((address_space(1))) unsigned int*)(gbase + idx * 1024 + lane * 16),
                (__attribute__((address_space(3))) unsigned int*)(lbase + idx * 1024 + lane * 16),
                16, 0, 0);
        }
    }
}

__global__ __launch_bounds__(NTHREADS) void router_main(
    const float* __restrict__ x, const char* __restrict__ wq,
    float* __restrict__ out, float* __restrict__ ws_accum)
{
    __shared__ __align__(16) char xpl[CHUNK_B];        // 3 x [64][72] bf16; reused as logits[64][68] f32
    __shared__ __align__(16) char wpl[2 * CHUNK_B];    // double-buffered W chunk (DMA target)
    __shared__ float smax[TM];
    __shared__ float sinvZ[TM];
    __shared__ float scount[NEXP];

    const int tid = threadIdx.x;
    const int wave = tid >> 6;
    const int lane = tid & 63;
    const int n0 = blockIdx.x * TM;

    f32x4 acc[4] = {{0.f, 0.f, 0.f, 0.f}, {0.f, 0.f, 0.f, 0.f},
                    {0.f, 0.f, 0.f, 0.f}, {0.f, 0.f, 0.f, 0.f}};

    float4 px0a, px0b, px1a, px1b;

    // prefetch chunk 0: W via DMA, x into regs
    dma_w_chunk(wq, wpl, wave, lane);
    load_x_slot(x, n0, 0, tid, px0a, px0b);
    load_x_slot(x, n0, 0, tid + NTHREADS, px1a, px1b);

    const int m = lane & 15;
    const int q = lane >> 4;
    const int aBase = (16 * wave + m) * RS + q * 8;    // bf16 index within a plane

#pragma unroll 1
    for (int c = 0; c < NCHUNK; ++c) {
        const int buf = c & 1;
        // stage x chunk c: convert fp32 -> 3 bf16 planes
        conv_store_x(xpl, tid, px0a, px0b);
        conv_store_x(xpl, tid + NTHREADS, px1a, px1b);
        __syncthreads();   // x planes visible; W DMA for chunk c already drained at prev barrier

        if (c + 1 < NCHUNK) {
            dma_w_chunk(wq + (size_t)(c + 1) * CHUNK_B, wpl + ((c + 1) & 1) * CHUNK_B, wave, lane);
            load_x_slot(x, n0, c + 1, tid, px0a, px0b);
            load_x_slot(x, n0, c + 1, tid + NTHREADS, px1a, px1b);
        }

        const unsigned short* xs = (const unsigned short*)xpl;
        const unsigned short* wb = (const unsigned short*)(wpl + buf * CHUNK_B);

#pragma unroll
        for (int kc = 0; kc < 2; ++kc) {
            const int ka = kc * 32;
            bhalf8 a1 = *(const bhalf8*)(xs + 0 * 4608 + aBase + ka);
            bhalf8 a2 = *(const bhalf8*)(xs + 1 * 4608 + aBase + ka);
            bhalf8 a3 = *(const bhalf8*)(xs + 2 * 4608 + aBase + ka);
#pragma unroll
            for (int t = 0; t < 4; ++t) {
                const int bo = (16 * t + m) * RS + q * 8 + ka;
                bhalf8 b1 = *(const bhalf8*)(wb + 0 * 4608 + bo);
                bhalf8 b2 = *(const bhalf8*)(wb + 1 * 4608 + bo);
                bhalf8 b3 = *(const bhalf8*)(wb + 2 * 4608 + bo);
                acc[t] = __builtin_amdgcn_mfma_f32_16x16x32_bf16(a1, b1, acc[t], 0, 0, 0);
                acc[t] = __builtin_amdgcn_mfma_f32_16x16x32_bf16(a1, b2, acc[t], 0, 0, 0);
                acc[t] = __builtin_amdgcn_mfma_f32_16x16x32_bf16(a2, b1, acc[t], 0, 0, 0);
                acc[t] = __builtin_amdgcn_mfma_f32_16x16x32_bf16(a1, b3, acc[t], 0, 0, 0);
                acc[t] = __builtin_amdgcn_mfma_f32_16x16x32_bf16(a2, b2, acc[t], 0, 0, 0);
                acc[t] = __builtin_amdgcn_mfma_f32_16x16x32_bf16(a3, b1, acc[t], 0, 0, 0);
                acc[t] = __builtin_amdgcn_mfma_f32_16x16x32_bf16(a2, b3, acc[t], 0, 0, 0);
                acc[t] = __builtin_amdgcn_mfma_f32_16x16x32_bf16(a3, b2, acc[t], 0, 0, 0);
                acc[t] = __builtin_amdgcn_mfma_f32_16x16x32_bf16(a3, b3, acc[t], 0, 0, 0);
            }
        }
        __syncthreads();   // waves done reading xpl/wpl[buf]; drains next chunk's DMA + x loads
    }

    // ---- epilogue: logits -> LDS (reuse xpl as logits[64][68] f32) ----
    float* logits = (float*)xpl;
    {
        const int col = lane & 15;
        const int rbase = (lane >> 4) * 4;     // C/D: row = (lane>>4)*4 + reg  [m89]
#pragma unroll
        for (int t = 0; t < 4; ++t)
#pragma unroll
            for (int r = 0; r < 4; ++r)
                logits[(16 * wave + rbase + r) * 68 + 16 * t + col] = acc[t][r];
    }
    if (tid < NEXP) scount[tid] = 0.f;
    __syncthreads();

    // phase A: per-token top-2 + softmax stats + weight/index writes
    if (tid < TM) {
        const int t = tid;
        float m1 = -3.4e38f, m2 = -3.4e38f;
        int i1 = 0, i2 = 0;
        for (int e = 0; e < NEXP; e++) {
            float v = logits[t * 68 + e];
            if (v > m1) { m2 = m1; i2 = i1; m1 = v; i1 = e; }
            else if (v > m2) { m2 = v; i2 = e; }
        }
        float Z = 0.f;
        for (int e = 0; e < NEXP; e++)
            Z += __expf(logits[t * 68 + e] - m1);
        float invZ = 1.f / Z;
        float p1 = invZ;
        float p2 = __expf(m2 - m1) * invZ;
        float denom = p1 + p2 + 1e-6f;
        int n = n0 + t;
        out[2 * n + 0] = p1 / denom;
        out[2 * n + 1] = p2 / denom;
        out[OUT_IDX_OFF + 2 * n + 0] = (float)i1;
        out[OUT_IDX_OFF + 2 * n + 1] = (float)i2;
        smax[t] = m1;
        sinvZ[t] = invZ;
        atomicAdd(&scount[i1], 1.f);
        atomicAdd(&scount[i2], 1.f);
    }
    __syncthreads();

    // phase B: per-expert prob sum over this block's tokens, then global atomics
    if (tid < NEXP) {
        const int e = tid;
        float s = 0.f;
        for (int t = 0; t < TM; t++)
            s += __expf(logits[t * 68 + e] - smax[t]) * sinvZ[t];
        atomicAdd(&ws_accum[e], s);
        atomicAdd(&ws_accum[NEXP + e], scount[e]);
    }
}

__global__ void router_finish(const float* __restrict__ ws_accum,
                              float* __restrict__ out)
{
    const int e = threadIdx.x;   // 64 threads = 1 wave
    const float invN = 1.f / (float)NTOK;
    float p = ws_accum[e] * invN;
    float a = ws_accum[NEXP + e] * invN;
    float v = p * p + a * a;
#pragma unroll
    for (int off = 32; off > 0; off >>= 1)
        v += __shfl_down(v, off);
    if (e == 0) out[OUT_AUX_OFF] = v * (float)NEXP;
    out[OUT_CNT_OFF + e] = ws_accum[NEXP + e];
}

extern "C" void kernel_launch(void* const* d_in, const int* in_sizes, int n_in,
                              void* d_out, int out_size, void* d_ws, size_t ws_size,
                              hipStream_t stream)
{
    const float* x = (const float*)d_in[0];   // [4,4096,2048] f32
    const float* W = (const float*)d_in[1];   // [64,2048] f32
    float* out = (float*)d_out;
    float* wsf = (float*)d_ws;
    char* wq = (char*)d_ws + WS_W_OFF;        // W planes: 32 chunks x 27648 B = 884736 B

    hipMemsetAsync(wsf, 0, 2 * NEXP * sizeof(float), stream);  // zero accum region
    wsplit_kernel<<<64, 256, 0, stream>>>(W, wq);
    router_main<<<NTOK / TM, NTHREADS, 0, stream>>>(x, wq, out, wsf);
    router_finish<<<1, 64, 0, stream>>>(wsf, out);
}

// Round 3
// 236.197 us; speedup vs baseline: 1.2173x; 1.0021x over previous
//
#include <hip/hip_runtime.h>

#define HID 2048
#define NEXP 64
#define NTOK 16384
#define TM 32            // tokens per block
#define NTHREADS 256
#define NCHUNK 32            // HID / 64
#define RS 72                // W plane row stride in bf16 elems (144 B)
#define PLANE_S 4608         // shorts per plane (64 experts * 72)
#define PLANE_B 9216
#define CHUNK_B 27648        // 3 planes = 27 x 1024 B (exact DMA multiple)
#define WS_W_OFF 1024        // W planes start here in d_ws (accum in [0,512))

// out layout (f32): weights [0,32768) | indices [32768,65536) | aux 65536 | counts [65537,65601)
#define OUT_IDX_OFF (2 * NTOK)
#define OUT_AUX_OFF (4 * NTOK)
#define OUT_CNT_OFF (4 * NTOK + 1)

typedef __attribute__((ext_vector_type(8))) short bhalf8;   // 8 bf16 = 4 VGPRs (MFMA A/B frag)
typedef __attribute__((ext_vector_type(4))) float f32x4;    // MFMA C/D frag

// Exact 3-way RNE bf16 split: v == h1 + h2 + h3 (24-bit significand fully captured).
__device__ __forceinline__ void split3(float v, unsigned short& h1, unsigned short& h2, unsigned short& h3) {
    unsigned int u = __float_as_uint(v);
    unsigned int r1 = (u + 0x7FFFu + ((u >> 16) & 1u)) & 0xFFFF0000u;
    float f1 = __uint_as_float(r1);
    float d1 = v - f1;
    unsigned int u2 = __float_as_uint(d1);
    unsigned int r2 = (u2 + 0x7FFFu + ((u2 >> 16) & 1u)) & 0xFFFF0000u;
    float f2 = __uint_as_float(r2);
    float d2 = d1 - f2;
    h1 = (unsigned short)(r1 >> 16);
    h2 = (unsigned short)(r2 >> 16);
    h3 = (unsigned short)(__float_as_uint(d2) >> 16);
}

// 8 fp32 -> three bf16x8 A-fragments, in registers (no LDS round-trip)
__device__ __forceinline__ void make_frags(float4 va, float4 vb, bhalf8& o1, bhalf8& o2, bhalf8& o3) {
    float f[8] = {va.x, va.y, va.z, va.w, vb.x, vb.y, vb.z, vb.w};
    union U { bhalf8 v; unsigned int u[4]; } u1, u2, u3;
#pragma unroll
    for (int t = 0; t < 4; t++) {
        unsigned short a1, a2, a3, b1, b2, b3;
        split3(f[2 * t], a1, a2, a3);
        split3(f[2 * t + 1], b1, b2, b3);
        u1.u[t] = (unsigned int)a1 | ((unsigned int)b1 << 16);
        u2.u[t] = (unsigned int)a2 | ((unsigned int)b2 << 16);
        u3.u[t] = (unsigned int)a3 | ((unsigned int)b3 << 16);
    }
    o1 = u1.v; o2 = u2.v; o3 = u3.v;
}

// ---- pre-kernel: split W into 3 bf16 planes in LDS-tile layout; also zeros accum ----
__global__ __launch_bounds__(256) void wsplit_kernel(const float* __restrict__ W,
                                                     char* __restrict__ wq,
                                                     float* __restrict__ wsf) {
    if (blockIdx.x == 0 && threadIdx.x < 2 * NEXP) wsf[threadIdx.x] = 0.f;
    int idx8 = (blockIdx.x * 256 + threadIdx.x) * 8;   // 16384 threads x 8 = 131072 elems
    int e = idx8 >> 11;
    int kk = idx8 & 2047;
    int c = kk >> 6;
    int j = kk & 63;
    const float4* wp = (const float4*)(W + (size_t)e * HID + kk);
    float4 v0 = wp[0], v1 = wp[1];
    float f[8] = {v0.x, v0.y, v0.z, v0.w, v1.x, v1.y, v1.z, v1.w};
    unsigned int p1[4], p2[4], p3[4];
#pragma unroll
    for (int t = 0; t < 4; t++) {
        unsigned short a1, a2, a3, b1, b2, b3;
        split3(f[2 * t], a1, a2, a3);
        split3(f[2 * t + 1], b1, b2, b3);
        p1[t] = (unsigned int)a1 | ((unsigned int)b1 << 16);
        p2[t] = (unsigned int)a2 | ((unsigned int)b2 << 16);
        p3[t] = (unsigned int)a3 | ((unsigned int)b3 << 16);
    }
    char* base = wq + (size_t)c * CHUNK_B + e * (RS * 2) + j * 2;
    *(uint4*)(base)               = make_uint4(p1[0], p1[1], p1[2], p1[3]);
    *(uint4*)(base + PLANE_B)     = make_uint4(p2[0], p2[1], p2[2], p2[3]);
    *(uint4*)(base + 2 * PLANE_B) = make_uint4(p3[0], p3[1], p3[2], p3[3]);
}

__device__ __forceinline__ void dma_w_chunk(const char* gbase, char* lbase, int wave, int lane) {
#pragma unroll
    for (int k = 0; k < 7; k++) {
        int idx = wave + 4 * k;       // 27 x 1024 B across 4 waves (wave-uniform guard)
        if (idx < 27) {
            __builtin_amdgcn_global_load_lds(
                (const __attribute__((address_space(1))) unsigned int*)(gbase + idx * 1024 + lane * 16),
                (__attribute__((address_space(3))) unsigned int*)(lbase + idx * 1024 + lane * 16),
                16, 0, 0);
        }
    }
}

__global__ __launch_bounds__(NTHREADS, 2) void router_main(
    const float* __restrict__ x, const char* __restrict__ wq,
    float* __restrict__ out, float* __restrict__ ws_accum)
{
    __shared__ __align__(16) char wpl[2 * CHUNK_B];    // 55296 B: double-buffered W chunk (DMA target)
    __shared__ float smax[TM];
    __shared__ float sinvZ[TM];
    __shared__ float scount[NEXP];

    const int tid = threadIdx.x;
    const int wave = tid >> 6;
    const int lane = tid & 63;
    const int m = lane & 15;          // A row / B expert-within-16
    const int q = lane >> 4;          // k-quad
    const int tokhalf = wave & 1;     // which 16 tokens
    const int exphalf = wave >> 1;    // which 32 experts
    const int n0 = blockIdx.x * TM;

    const float* xrow = x + (size_t)(n0 + tokhalf * 16 + m) * HID + q * 8;

    f32x4 acc[2][2] = {{{0.f,0.f,0.f,0.f},{0.f,0.f,0.f,0.f}},
                       {{0.f,0.f,0.f,0.f},{0.f,0.f,0.f,0.f}}};   // [t][kc] partials

    // prefetch chunk 0: W via LDS-DMA, x into regs
    dma_w_chunk(wq, wpl, wave, lane);
    float4 px[2][2];
    px[0][0] = *(const float4*)(xrow);
    px[0][1] = *(const float4*)(xrow + 4);
    px[1][0] = *(const float4*)(xrow + 32);
    px[1][1] = *(const float4*)(xrow + 36);

#pragma unroll 1
    for (int c = 0; c < NCHUNK; ++c) {
        __syncthreads();   // drains this chunk's DMA (vmcnt(0) before s_barrier)
        if (c + 1 < NCHUNK)
            dma_w_chunk(wq + (size_t)(c + 1) * CHUNK_B, wpl + ((c + 1) & 1) * CHUNK_B, wave, lane);

        // convert prefetched x -> A-frags in registers
        bhalf8 A[2][3];
        make_frags(px[0][0], px[0][1], A[0][0], A[0][1], A[0][2]);
        make_frags(px[1][0], px[1][1], A[1][0], A[1][1], A[1][2]);

        if (c + 1 < NCHUNK) {
            const float* xp = xrow + (c + 1) * 64;
            px[0][0] = *(const float4*)(xp);
            px[0][1] = *(const float4*)(xp + 4);
            px[1][0] = *(const float4*)(xp + 32);
            px[1][1] = *(const float4*)(xp + 36);
        }

        const unsigned short* wb = (const unsigned short*)(wpl + (c & 1) * CHUNK_B);
#pragma unroll
        for (int kc = 0; kc < 2; ++kc) {
#pragma unroll
            for (int t = 0; t < 2; ++t) {
                const int bo = (exphalf * 32 + t * 16 + m) * RS + kc * 32 + q * 8;
                bhalf8 b1 = *(const bhalf8*)(wb + 0 * PLANE_S + bo);
                bhalf8 b2 = *(const bhalf8*)(wb + 1 * PLANE_S + bo);
                bhalf8 b3 = *(const bhalf8*)(wb + 2 * PLANE_S + bo);
                f32x4 a4 = acc[t][kc];
                a4 = __builtin_amdgcn_mfma_f32_16x16x32_bf16(A[kc][0], b1, a4, 0, 0, 0);
                a4 = __builtin_amdgcn_mfma_f32_16x16x32_bf16(A[kc][0], b2, a4, 0, 0, 0);
                a4 = __builtin_amdgcn_mfma_f32_16x16x32_bf16(A[kc][1], b1, a4, 0, 0, 0);
                a4 = __builtin_amdgcn_mfma_f32_16x16x32_bf16(A[kc][0], b3, a4, 0, 0, 0);
                a4 = __builtin_amdgcn_mfma_f32_16x16x32_bf16(A[kc][1], b2, a4, 0, 0, 0);
                a4 = __builtin_amdgcn_mfma_f32_16x16x32_bf16(A[kc][2], b1, a4, 0, 0, 0);
                a4 = __builtin_amdgcn_mfma_f32_16x16x32_bf16(A[kc][1], b3, a4, 0, 0, 0);
                a4 = __builtin_amdgcn_mfma_f32_16x16x32_bf16(A[kc][2], b2, a4, 0, 0, 0);
                a4 = __builtin_amdgcn_mfma_f32_16x16x32_bf16(A[kc][2], b3, a4, 0, 0, 0);
                acc[t][kc] = a4;
            }
        }
    }

    // ---- epilogue: logits -> LDS buf0 (last K-chunk used buf1; disjoint) ----
    float* logits = (float*)wpl;   // [32][68] f32 = 8704 B
    {
        const int col = lane & 15;
        const int rbase = (lane >> 4) * 4;   // C/D: row = (lane>>4)*4 + reg  [m89]
#pragma unroll
        for (int t = 0; t < 2; ++t)
#pragma unroll
            for (int r = 0; r < 4; ++r)
                logits[(tokhalf * 16 + rbase + r) * 68 + exphalf * 32 + t * 16 + col] =
                    acc[t][0][r] + acc[t][1][r];
    }
    if (tid < NEXP) scount[tid] = 0.f;
    __syncthreads();

    // phase A: per-token top-2 + softmax stats + weight/index writes
    if (tid < TM) {
        const int t = tid;
        float m1 = -3.4e38f, m2 = -3.4e38f;
        int i1 = 0, i2 = 0;
        for (int e = 0; e < NEXP; e++) {
            float v = logits[t * 68 + e];
            if (v > m1) { m2 = m1; i2 = i1; m1 = v; i1 = e; }
            else if (v > m2) { m2 = v; i2 = e; }
        }
        float Z = 0.f;
        for (int e = 0; e < NEXP; e++)
            Z += __expf(logits[t * 68 + e] - m1);
        float invZ = 1.f / Z;
        float p1 = invZ;
        float p2 = __expf(m2 - m1) * invZ;
        float denom = p1 + p2 + 1e-6f;
        int n = n0 + t;
        out[2 * n + 0] = p1 / denom;
        out[2 * n + 1] = p2 / denom;
        out[OUT_IDX_OFF + 2 * n + 0] = (float)i1;
        out[OUT_IDX_OFF + 2 * n + 1] = (float)i2;
        smax[t] = m1;
        sinvZ[t] = invZ;
        atomicAdd(&scount[i1], 1.f);
        atomicAdd(&scount[i2], 1.f);
    }
    __syncthreads();

    // phase B: per-expert prob sum over this block's tokens, then global atomics
    if (tid < NEXP) {
        const int e = tid;
        float s = 0.f;
        for (int t = 0; t < TM; t++)
            s += __expf(logits[t * 68 + e] - smax[t]) * sinvZ[t];
        atomicAdd(&ws_accum[e], s);
        atomicAdd(&ws_accum[NEXP + e], scount[e]);
    }
}

__global__ void router_finish(const float* __restrict__ ws_accum,
                              float* __restrict__ out)
{
    const int e = threadIdx.x;   // 64 threads = 1 wave
    const float invN = 1.f / (float)NTOK;
    float p = ws_accum[e] * invN;
    float a = ws_accum[NEXP + e] * invN;
    float v = p * p + a * a;
#pragma unroll
    for (int off = 32; off > 0; off >>= 1)
        v += __shfl_down(v, off);
    if (e == 0) out[OUT_AUX_OFF] = v * (float)NEXP;
    out[OUT_CNT_OFF + e] = ws_accum[NEXP + e];
}

extern "C" void kernel_launch(void* const* d_in, const int* in_sizes, int n_in,
                              void* d_out, int out_size, void* d_ws, size_t ws_size,
                              hipStream_t stream)
{
    const float* x = (const float*)d_in[0];   // [4,4096,2048] f32
    const float* W = (const float*)d_in[1];   // [64,2048] f32
    float* out = (float*)d_out;
    float* wsf = (float*)d_ws;
    char* wq = (char*)d_ws + WS_W_OFF;        // W planes: 32 chunks x 27648 B

    wsplit_kernel<<<64, 256, 0, stream>>>(W, wq, wsf);   // also zeros accum region
    router_main<<<NTOK / TM, NTHREADS, 0, stream>>>(x, wq, out, wsf);
    router_finish<<<1, 64, 0, stream>>>(wsf, out);
}

// Round 4
// 217.460 us; speedup vs baseline: 1.3222x; 1.0862x over previous
//
#include <hip/hip_runtime.h>

#define HID 2048
#define NEXP 64
#define NTOK 16384
#define TM 32            // tokens per block (one 32-row MFMA tile)
#define NTHREADS 256
#define NCHUNK 32        // HID / 64
#define KPH 4            // K-phases = waves per block
#define CPW 8            // chunks per wave (NCHUNK / KPH)
#define WS_W_OFF 1024    // W planes start here in d_ws (accum in [0,512))
#define CHUNK_B 24576    // 4 ksteps * 3 planes * 2 halves * 1024 B

// out layout (f32): weights [0,32768) | indices [32768,65536) | aux 65536 | counts [65537,65601)
#define OUT_IDX_OFF (2 * NTOK)
#define OUT_AUX_OFF (4 * NTOK)
#define OUT_CNT_OFF (4 * NTOK + 1)

typedef __attribute__((ext_vector_type(8))) short bhalf8;    // 8 bf16 = 4 VGPRs (A/B frag)
typedef __attribute__((ext_vector_type(16))) float f32x16;   // 32x32 C/D frag

// Exact 3-way RNE bf16 split (for W, precomputed): v == h1+h2+h3 exactly.
__device__ __forceinline__ void split3(float v, unsigned short& h1, unsigned short& h2, unsigned short& h3) {
    unsigned int u = __float_as_uint(v);
    unsigned int r1 = (u + 0x7FFFu + ((u >> 16) & 1u)) & 0xFFFF0000u;
    float f1 = __uint_as_float(r1);
    float d1 = v - f1;
    unsigned int u2 = __float_as_uint(d1);
    unsigned int r2 = (u2 + 0x7FFFu + ((u2 >> 16) & 1u)) & 0xFFFF0000u;
    float f2 = __uint_as_float(r2);
    float d2 = d1 - f2;
    h1 = (unsigned short)(r1 >> 16);
    h2 = (unsigned short)(r2 >> 16);
    h3 = (unsigned short)(__float_as_uint(d2) >> 16);
}

// Truncating 3-plane split of 8 fp32 -> three bf16x8 A-frags, in registers.
// Residual <= 2^-21 |x| (dropped); cheap: 4 sub/and + pack per pair.
__device__ __forceinline__ void xsplit(float4 va, float4 vb, bhalf8& o1, bhalf8& o2, bhalf8& o3) {
    float f[8] = {va.x, va.y, va.z, va.w, vb.x, vb.y, vb.z, vb.w};
    union U { bhalf8 v; unsigned int u[4]; } u1, u2, u3;
#pragma unroll
    for (int t = 0; t < 4; t++) {
        float a = f[2 * t], b = f[2 * t + 1];
        unsigned int ua = __float_as_uint(a), ub = __float_as_uint(b);
        float da = a - __uint_as_float(ua & 0xFFFF0000u);
        float db = b - __uint_as_float(ub & 0xFFFF0000u);
        unsigned int uda = __float_as_uint(da), udb = __float_as_uint(db);
        float da2 = da - __uint_as_float(uda & 0xFFFF0000u);
        float db2 = db - __uint_as_float(udb & 0xFFFF0000u);
        u1.u[t] = (ua >> 16) | (ub & 0xFFFF0000u);
        u2.u[t] = (uda >> 16) | (udb & 0xFFFF0000u);
        u3.u[t] = (__float_as_uint(da2) >> 16) | (__float_as_uint(db2) & 0xFFFF0000u);
    }
    o1 = u1.v; o2 = u2.v; o3 = u3.v;
}

// ---- pre-kernel: split W into 3 bf16 planes in coalesced B-fragment layout ----
// byte offset = (((c*4+ks)*3 + p)*2 + half)*1024 + lane*16
//   where expert e = (lane&31) + 32*g?  No: B-frag lane l -> expert = lane&31 + ... see router.
//   lane l covers expert n=(l&31) of group g via separate 1024-B panels? Here: per (c,ks,p)
//   two 1024-B panels indexed by half=(k>>3)&1... lane*16 with lane = (e&31) + 32*half.
// Router reads panel g at +g*1024?  -> panels are [g][lane]: lane=(e&31)+32*((k>>3)&1) covers
// 32 experts x 2 k-octets = 64 lanes * 16 B = 1024 B, g selects expert group.
__global__ __launch_bounds__(256) void wsplit_kernel(const float* __restrict__ W,
                                                     char* __restrict__ wq,
                                                     float* __restrict__ wsf) {
    if (blockIdx.x == 0 && threadIdx.x < 2 * NEXP) wsf[threadIdx.x] = 0.f;
    int idx8 = (blockIdx.x * 256 + threadIdx.x) * 8;   // 16384 threads x 8 elems
    int e = idx8 >> 11;
    int k0 = idx8 & 2047;                // octet-aligned k
    int c = k0 >> 6, ks = (k0 >> 4) & 3, half = (k0 >> 3) & 1;
    int g = e >> 5, l = (e & 31) + 32 * half;
    const float4* wp = (const float4*)(W + (size_t)e * HID + k0);
    float4 v0 = wp[0], v1 = wp[1];
    float f[8] = {v0.x, v0.y, v0.z, v0.w, v1.x, v1.y, v1.z, v1.w};
    unsigned int p1[4], p2[4], p3[4];
#pragma unroll
    for (int t = 0; t < 4; t++) {
        unsigned short a1, a2, a3, b1, b2, b3;
        split3(f[2 * t], a1, a2, a3);
        split3(f[2 * t + 1], b1, b2, b3);
        p1[t] = (unsigned int)a1 | ((unsigned int)b1 << 16);
        p2[t] = (unsigned int)a2 | ((unsigned int)b2 << 16);
        p3[t] = (unsigned int)a3 | ((unsigned int)b3 << 16);
    }
    char* base = wq + (size_t)(((c * 4 + ks) * 3 + 0) * 2 + g) * 1024 + l * 16;
    *(uint4*)(base)        = make_uint4(p1[0], p1[1], p1[2], p1[3]);   // plane 1 (+0*2048)
    *(uint4*)(base + 2048) = make_uint4(p2[0], p2[1], p2[2], p2[3]);   // plane 2
    *(uint4*)(base + 4096) = make_uint4(p3[0], p3[1], p3[2], p3[3]);   // plane 3
}

__global__ __launch_bounds__(NTHREADS, 2) void router_main(
    const float* __restrict__ x, const char* __restrict__ wq,
    float* __restrict__ out, float* __restrict__ ws_accum)
{
    __shared__ float slab[KPH * TM * 68];   // 34816 B: per-kphase partial logits
    __shared__ float smax[TM];
    __shared__ float sinvZ[TM];
    __shared__ float scount[NEXP];

    const int tid = threadIdx.x;
    const int w = tid >> 6;        // kphase
    const int lane = tid & 63;
    const int r = lane & 31;       // A row / token within tile; B expert within group
    const int h = lane >> 5;       // k-octet half
    const int n0 = blockIdx.x * TM;

    const float* xrow = x + (size_t)(n0 + r) * HID + h * 8;

    f32x16 acc0, acc1;
#pragma unroll
    for (int i = 0; i < 16; i++) { acc0[i] = 0.f; acc1[i] = 0.f; }

    // ---- free-running K-loop: no LDS, no barriers ----
#pragma unroll 1
    for (int i = 0; i < CPW; ++i) {
        const int c = w * CPW + i;
        const float* xc = xrow + c * 64;
        float4 pxa[4], pxb[4];
#pragma unroll
        for (int ks = 0; ks < 4; ks++) {
            pxa[ks] = *(const float4*)(xc + ks * 16);
            pxb[ks] = *(const float4*)(xc + ks * 16 + 4);
        }
        const char* wc = wq + (size_t)c * CHUNK_B + lane * 16;
#pragma unroll
        for (int ks = 0; ks < 4; ks++) {
            bhalf8 A1, A2, A3;
            xsplit(pxa[ks], pxb[ks], A1, A2, A3);
            const char* wk = wc + ks * 6144;
            {   // expert group 0
                bhalf8 B1 = *(const bhalf8*)(wk);
                bhalf8 B2 = *(const bhalf8*)(wk + 2048);
                bhalf8 B3 = *(const bhalf8*)(wk + 4096);
                acc0 = __builtin_amdgcn_mfma_f32_32x32x16_bf16(A1, B1, acc0, 0, 0, 0);
                acc0 = __builtin_amdgcn_mfma_f32_32x32x16_bf16(A1, B2, acc0, 0, 0, 0);
                acc0 = __builtin_amdgcn_mfma_f32_32x32x16_bf16(A2, B1, acc0, 0, 0, 0);
                acc0 = __builtin_amdgcn_mfma_f32_32x32x16_bf16(A1, B3, acc0, 0, 0, 0);
                acc0 = __builtin_amdgcn_mfma_f32_32x32x16_bf16(A2, B2, acc0, 0, 0, 0);
                acc0 = __builtin_amdgcn_mfma_f32_32x32x16_bf16(A3, B1, acc0, 0, 0, 0);
            }
            {   // expert group 1
                bhalf8 B1 = *(const bhalf8*)(wk + 1024);
                bhalf8 B2 = *(const bhalf8*)(wk + 2048 + 1024);
                bhalf8 B3 = *(const bhalf8*)(wk + 4096 + 1024);
                acc1 = __builtin_amdgcn_mfma_f32_32x32x16_bf16(A1, B1, acc1, 0, 0, 0);
                acc1 = __builtin_amdgcn_mfma_f32_32x32x16_bf16(A1, B2, acc1, 0, 0, 0);
                acc1 = __builtin_amdgcn_mfma_f32_32x32x16_bf16(A2, B1, acc1, 0, 0, 0);
                acc1 = __builtin_amdgcn_mfma_f32_32x32x16_bf16(A1, B3, acc1, 0, 0, 0);
                acc1 = __builtin_amdgcn_mfma_f32_32x32x16_bf16(A2, B2, acc1, 0, 0, 0);
                acc1 = __builtin_amdgcn_mfma_f32_32x32x16_bf16(A3, B1, acc1, 0, 0, 0);
            }
        }
    }

    // ---- combine: each wave stores its partial tile to its slab ----
    // C/D 32x32 layout: col = lane&31, row = (reg&3) + 8*(reg>>2) + 4*(lane>>5)  [m74/m101]
#pragma unroll
    for (int reg = 0; reg < 16; reg++) {
        int row = (reg & 3) + 8 * (reg >> 2) + 4 * h;
        slab[(w * TM + row) * 68 + r]      = acc0[reg];
        slab[(w * TM + row) * 68 + 32 + r] = acc1[reg];
    }
    if (tid < NEXP) scount[tid] = 0.f;
    __syncthreads();

    // reduce 4 kphase slabs into slab[0] (each (t,e) owned by exactly one thread)
    float* logits = slab;
#pragma unroll
    for (int idx = tid; idx < TM * NEXP; idx += NTHREADS) {
        int t = idx >> 6, e = idx & 63;
        float v = slab[(0 * TM + t) * 68 + e] + slab[(1 * TM + t) * 68 + e]
                + slab[(2 * TM + t) * 68 + e] + slab[(3 * TM + t) * 68 + e];
        logits[t * 68 + e] = v;
    }
    __syncthreads();

    // phase A: per-token top-2 + softmax stats + weight/index writes
    if (tid < TM) {
        const int t = tid;
        float m1 = -3.4e38f, m2 = -3.4e38f;
        int i1 = 0, i2 = 0;
        for (int e = 0; e < NEXP; e++) {
            float v = logits[t * 68 + e];
            if (v > m1) { m2 = m1; i2 = i1; m1 = v; i1 = e; }
            else if (v > m2) { m2 = v; i2 = e; }
        }
        float Z = 0.f;
        for (int e = 0; e < NEXP; e++)
            Z += __expf(logits[t * 68 + e] - m1);
        float invZ = 1.f / Z;
        float p1 = invZ;
        float p2 = __expf(m2 - m1) * invZ;
        float denom = p1 + p2 + 1e-6f;
        int n = n0 + t;
        out[2 * n + 0] = p1 / denom;
        out[2 * n + 1] = p2 / denom;
        out[OUT_IDX_OFF + 2 * n + 0] = (float)i1;
        out[OUT_IDX_OFF + 2 * n + 1] = (float)i2;
        smax[t] = m1;
        sinvZ[t] = invZ;
        atomicAdd(&scount[i1], 1.f);
        atomicAdd(&scount[i2], 1.f);
    }
    __syncthreads();

    // phase B: per-expert prob sum over this block's tokens, then global atomics
    if (tid < NEXP) {
        const int e = tid;
        float s = 0.f;
        for (int t = 0; t < TM; t++)
            s += __expf(logits[t * 68 + e] - smax[t]) * sinvZ[t];
        atomicAdd(&ws_accum[e], s);
        atomicAdd(&ws_accum[NEXP + e], scount[e]);
    }
}

__global__ void router_finish(const float* __restrict__ ws_accum,
                              float* __restrict__ out)
{
    const int e = threadIdx.x;   // 64 threads = 1 wave
    const float invN = 1.f / (float)NTOK;
    float p = ws_accum[e] * invN;
    float a = ws_accum[NEXP + e] * invN;
    float v = p * p + a * a;
#pragma unroll
    for (int off = 32; off > 0; off >>= 1)
        v += __shfl_down(v, off);
    if (e == 0) out[OUT_AUX_OFF] = v * (float)NEXP;
    out[OUT_CNT_OFF + e] = ws_accum[NEXP + e];
}

extern "C" void kernel_launch(void* const* d_in, const int* in_sizes, int n_in,
                              void* d_out, int out_size, void* d_ws, size_t ws_size,
                              hipStream_t stream)
{
    const float* x = (const float*)d_in[0];   // [4,4096,2048] f32
    const float* W = (const float*)d_in[1];   // [64,2048] f32
    float* out = (float*)d_out;
    float* wsf = (float*)d_ws;
    char* wq = (char*)d_ws + WS_W_OFF;        // W planes: 32 chunks x 24576 B = 768 KB

    wsplit_kernel<<<64, 256, 0, stream>>>(W, wq, wsf);   // also zeros accum region
    router_main<<<NTOK / TM, NTHREADS, 0, stream>>>(x, wq, out, wsf);
    router_finish<<<1, 64, 0, stream>>>(wsf, out);
}